// Round 12
// baseline (625.354 us; speedup 1.0000x reference)
//
#include <hip/hip_runtime.h>
#include <math.h>

#define NPTS 12288
#define DIM 64
#define KNN 85
#define KSEL 86          // 85 neighbors + self
#define SAMPLE 2000
#define SSTRIDE 6        // deterministic sample: idx = 6*p, p in [0,2000)
#define GAMMA 0.5f
#define NT 256           // block size (4 waves)
#define WPB 4            // waves per block
#define VIT 12           // iterations: 12*256 threads*4 pts = 12288
#define LCAP 128         // per-wave candidate capacity (~88-92 expected)
#define VCAP 96          // block-level valid-neighbor capacity (<=85 real)
#define PT 32            // pearson tile (32x32, union LDS < 20 KB)
#define PPITCH 36        // padded LDS pitch (floats), 16B-aligned
#define PGRID 63         // ceil(2000/32)
#define PBLKS (PGRID * PGRID)
#define TOTAL_BLOCKS (NPTS + PBLKS)

// ws layout: acc[0..36] doubles; done-counter (unsigned) right after.
// acc: [0..4] pearson sums; [5..36] spread slots for local-loss partials

// identical d2 in every pass: same inlined fmaf sequence -> same codegen,
// so recomputed values are bit-stable across the 3 streaming passes.
__device__ __forceinline__ float d2f(float x, float y, float z,
                                     float qx, float qy, float qz) {
  float dx = qx - x, dy = qy - y, dz = qz - z;
  return fmaf(dx, dx, fmaf(dy, dy, dz * dz));
}

// exact wave-local radix select (4x8-bit passes); 0xFFFFFFFF = padding, skipped.
// h = wave-private 256-bin LDS histogram (wave-internal DS ordering only).
template <int NV_>
__device__ __forceinline__ unsigned wave_select4(const unsigned v[NV_], unsigned want,
                                                 unsigned* h, int lane) {
  unsigned prefix = 0;
  #pragma unroll
  for (int pass = 0; pass < 4; ++pass) {
    const int shift = 24 - 8 * pass;
    const unsigned hmask = pass ? (0xFFFFFFFFu << (shift + 8)) : 0u;
    h[lane] = 0; h[lane + 64] = 0; h[lane + 128] = 0; h[lane + 192] = 0;
    __builtin_amdgcn_wave_barrier();
    #pragma unroll
    for (int t = 0; t < NV_; ++t) {
      unsigned u = v[t];
      if (u != 0xFFFFFFFFu && (u & hmask) == prefix)
        atomicAdd(&h[(u >> shift) & 255u], 1u);
    }
    __builtin_amdgcn_wave_barrier();
    unsigned c0 = h[4 * lane], c1 = h[4 * lane + 1];
    unsigned c2 = h[4 * lane + 2], c3 = h[4 * lane + 3];
    unsigned lt = c0 + c1 + c2 + c3;
    unsigned incl = lt;
    #pragma unroll
    for (int off = 1; off < 64; off <<= 1) {
      unsigned t2 = __shfl_up(incl, off, 64);
      if (lane >= off) incl += t2;
    }
    unsigned excl = incl - lt;
    bool has = (lt > 0) && (excl < want) && (want <= incl);
    unsigned bin = 4 * lane, below = excl, cum = excl;
    if (cum + c0 >= want) { bin = 4 * lane; below = cum; }
    else { cum += c0;
      if (cum + c1 >= want) { bin = 4 * lane + 1; below = cum; }
      else { cum += c1;
        if (cum + c2 >= want) { bin = 4 * lane + 2; below = cum; }
        else { cum += c2; bin = 4 * lane + 3; below = cum; } } }
    unsigned long long bal = __ballot(has);
    int src = __ffsll((unsigned long long)bal) - 1;
    bin = __shfl(bin, src, 64);
    below = __shfl(below, src, 64);
    prefix |= bin << shift;
    want -= below;
  }
  return prefix;
}

// Single fused kernel. blocks [0,NPTS): knn/local-loss (streaming recompute,
// no d2b array -> live set ~40 VGPR -> the (256,8) cap is safe; spill
// tripwire = WRITE_SIZE). blocks [NPTS,TOTAL): pearson tiles. Last finished
// block (device-scope done-counter) computes the final scalar.
__global__ __launch_bounds__(NT, 8) void fused_kernel(
    const float* __restrict__ emb, const float* __restrict__ coord,
    double* __restrict__ acc, float* __restrict__ out) {
  __shared__ union SM {
    struct {
      unsigned hist[WPB][256];       // 4 KiB
      unsigned nbu[WPB][LCAP];       // 2 KiB
      unsigned short nbj[WPB][LCAP]; // 1 KiB
      unsigned wcnt[WPB];
      unsigned vn_u[VCAP];
      unsigned short vn_j[VCAP];
      unsigned vcnt;
      unsigned selg;
    } k;
    struct {
      float EpT[DIM][PPITCH];        // 9 KiB (transposed tile)
      float EqT[DIM][PPITCH];        // 9 KiB
      float Cp[PT][4];
      float Cq[PT][4];
      double wred[4][5];
    } p;
  } sm;

  const int tid = threadIdx.x;
  const int lane = tid & 63;
  const int wv = tid >> 6;
  unsigned* cnt = (unsigned*)(acc + 37);

  if (blockIdx.x < NPTS) {
    // ================= KNN / local-loss body (streaming) ====================
    const int i = blockIdx.x;
    const float qx = coord[3 * i], qy = coord[3 * i + 1], qz = coord[3 * i + 2];
    const float4* C4 = (const float4*)coord;   // 4 pts = 3 float4s, free deint

    // ---- pass A: per-lane two smallest (uint order == float order) ----
    unsigned m1 = 0xFFFFFFFFu, m2 = 0xFFFFFFFFu;
    #pragma unroll 1
    for (int it = 0; it < VIT; ++it) {
      int p = it * NT + tid;
      float4 f0 = C4[3 * p], f1 = C4[3 * p + 1], f2 = C4[3 * p + 2];
      float dd[4];
      dd[0] = d2f(f0.x, f0.y, f0.z, qx, qy, qz);
      dd[1] = d2f(f0.w, f1.x, f1.y, qx, qy, qz);
      dd[2] = d2f(f1.z, f1.w, f2.x, qx, qy, qz);
      dd[3] = d2f(f2.y, f2.z, f2.w, qx, qy, qz);
      #pragma unroll
      for (int c = 0; c < 4; ++c) {
        unsigned u = __float_as_uint(dd[c]);
        unsigned hi = u > m1 ? u : m1;
        m1 = u < m1 ? u : m1;
        m2 = hi < m2 ? hi : m2;
      }
    }
    // M2 = wave-max of 2nd-smallest: >=128 values <= M2 => wave-86th <= M2
    unsigned M2 = m2;
    #pragma unroll
    for (int off = 32; off > 0; off >>= 1) {
      unsigned t2 = __shfl_xor((int)M2, off, 64);
      M2 = t2 > M2 ? t2 : M2;
    }
    const float M2f = __uint_as_float(M2);
    const float sbin = 256.0f / fmaxf(M2f, 1e-30f);

    // ---- pass B: linear-binned histogram of values <= M2 (recompute) ----
    unsigned* h = sm.k.hist[wv];
    h[lane] = 0; h[lane + 64] = 0; h[lane + 128] = 0; h[lane + 192] = 0;
    __builtin_amdgcn_wave_barrier();
    #pragma unroll 1
    for (int it = 0; it < VIT; ++it) {
      int p = it * NT + tid;
      float4 f0 = C4[3 * p], f1 = C4[3 * p + 1], f2 = C4[3 * p + 2];
      float dd[4];
      dd[0] = d2f(f0.x, f0.y, f0.z, qx, qy, qz);
      dd[1] = d2f(f0.w, f1.x, f1.y, qx, qy, qz);
      dd[2] = d2f(f1.z, f1.w, f2.x, qx, qy, qz);
      dd[3] = d2f(f2.y, f2.z, f2.w, qx, qy, qz);
      #pragma unroll
      for (int c = 0; c < 4; ++c) {
        if (__float_as_uint(dd[c]) <= M2) {
          int b = (int)(dd[c] * sbin);
          b = b > 255 ? 255 : b;
          atomicAdd(&h[b], 1u);
        }
      }
    }
    __builtin_amdgcn_wave_barrier();
    unsigned c0 = h[4 * lane], c1 = h[4 * lane + 1];
    unsigned c2 = h[4 * lane + 2], c3 = h[4 * lane + 3];
    unsigned lt = c0 + c1 + c2 + c3;
    unsigned incl = lt;
    #pragma unroll
    for (int off = 1; off < 64; off <<= 1) {
      unsigned t2 = __shfl_up(incl, off, 64);
      if (lane >= off) incl += t2;
    }
    unsigned excl = incl - lt;
    bool has = (lt > 0) && (excl < KSEL) && (KSEL <= incl);
    unsigned bin = 4 * lane, cum = excl;
    if (cum + c0 >= KSEL) { bin = 4 * lane; }
    else { cum += c0;
      if (cum + c1 >= KSEL) { bin = 4 * lane + 1; }
      else { cum += c1;
        if (cum + c2 >= KSEL) { bin = 4 * lane + 2; }
        else { bin = 4 * lane + 3; } } }
    unsigned long long bal = __ballot(has);
    int src = __ffsll((unsigned long long)bal) - 1;
    unsigned bsel = __shfl((int)bin, src, 64);
    // inclusive upper edge of selected bucket (32-ulp safety margin up also
    // absorbs any recompute bit-divergence between passes)
    float Uf = (float)(bsel + 1) * (M2f * (1.0f / 256.0f)) * 1.000002f;
    const unsigned U = __float_as_uint(Uf);

    // ---- pass C: append candidates d2 <= U (recompute; ~88-92 per wave) ----
    if (lane == 0) sm.k.wcnt[wv] = 0;
    if (tid == 0) sm.k.vcnt = 0;
    __builtin_amdgcn_wave_barrier();
    #pragma unroll 1
    for (int it = 0; it < VIT; ++it) {
      int p = it * NT + tid;
      float4 f0 = C4[3 * p], f1 = C4[3 * p + 1], f2 = C4[3 * p + 2];
      float dd[4];
      dd[0] = d2f(f0.x, f0.y, f0.z, qx, qy, qz);
      dd[1] = d2f(f0.w, f1.x, f1.y, qx, qy, qz);
      dd[2] = d2f(f1.z, f1.w, f2.x, qx, qy, qz);
      dd[3] = d2f(f2.y, f2.z, f2.w, qx, qy, qz);
      #pragma unroll
      for (int c = 0; c < 4; ++c) {
        unsigned u = __float_as_uint(dd[c]);
        if (u <= U) {
          unsigned pos = atomicAdd(&sm.k.wcnt[wv], 1u);
          if (pos < LCAP) {
            sm.k.nbu[wv][pos] = u;
            sm.k.nbj[wv][pos] = (unsigned short)(4 * p + c);
          }
        }
      }
    }
    __syncthreads();   // barrier 1: lists + vcnt=0 visible

    // ---- wave 0 only: exact global 86th among the union ----
    if (wv == 0) {
      unsigned mv[2 * WPB];
      #pragma unroll
      for (int w = 0; w < WPB; ++w) {
        unsigned mw = sm.k.wcnt[w] < LCAP ? sm.k.wcnt[w] : LCAP;
        mv[2 * w]     = ((unsigned)lane < mw)      ? sm.k.nbu[w][lane]      : 0xFFFFFFFFu;
        mv[2 * w + 1] = ((unsigned)lane + 64 < mw) ? sm.k.nbu[w][lane + 64] : 0xFFFFFFFFu;
      }
      unsigned t = wave_select4<2 * WPB>(mv, KSEL, sm.k.hist[0], lane);
      if (lane == 0) sm.k.selg = t;
    }
    __syncthreads();   // barrier 2: threshold visible
    const unsigned thrg = sm.k.selg;

    // ---- compact the true 85 neighbors into one block-level list ----
    const int mw = (int)(sm.k.wcnt[wv] < LCAP ? sm.k.wcnt[wv] : LCAP);
    for (int n = lane; n < mw; n += 64) {
      unsigned u = sm.k.nbu[wv][n];
      int j = (int)sm.k.nbj[wv][n];
      if (u <= thrg && j != i) {
        unsigned p = atomicAdd(&sm.k.vcnt, 1u);
        if (p < VCAP) { sm.k.vn_u[p] = u; sm.k.vn_j[p] = (unsigned short)j; }
      }
    }
    __syncthreads();   // barrier 3: valid list visible
    const int tot = (int)(sm.k.vcnt < VCAP ? sm.k.vcnt : VCAP);

    // ---- loss: 16 neighbors per block-iteration (4 waves x 4 quarters) ----
    const int q = lane >> 4;
    const int l16 = lane & 15;
    const float4 ei4 = ((const float4*)(emb + (size_t)i * DIM))[l16];
    float lsum = 0.f;
    for (int base = wv * 4; base < tot; base += 16) {  // wave-uniform trips
      int idx = base + q;
      bool valid = idx < tot;
      unsigned u = 0; int j = 0;
      if (valid) { u = sm.k.vn_u[idx]; j = (int)sm.k.vn_j[idx]; }
      float s = 0.f;
      if (valid) {
        float4 e4 = ((const float4*)(emb + (size_t)j * DIM))[l16];
        float d0 = ei4.x - e4.x, d1 = ei4.y - e4.y;
        float d2 = ei4.z - e4.z, d3 = ei4.w - e4.w;
        s = d0 * d0 + d1 * d1 + d2 * d2 + d3 * d3;
      }
      s += __shfl_xor(s, 1, 64);
      s += __shfl_xor(s, 2, 64);
      s += __shfl_xor(s, 4, 64);
      s += __shfl_xor(s, 8, 64);
      if (valid && l16 == 0) {
        float td = sqrtf(__uint_as_float(u));
        float pd = sqrtf(fmaxf(s, 0.f));
        float diff = pd - td;
        lsum += diff * diff * expf(-GAMMA * td);
      }
    }
    #pragma unroll
    for (int off = 32; off > 0; off >>= 1) lsum += __shfl_xor(lsum, off, 64);
    if (lane == 0) atomicAdd(&acc[5 + (blockIdx.x & 7) * 4 + wv], (double)lsum);

  } else {
    // ================= Pearson tile body (32x32, 2x2 blocking) ==============
    const int bid = blockIdx.x - NPTS;
    const int tx = tid & 15, ty = tid >> 4;
    const int p0 = (bid / PGRID) * PT, q0 = (bid % PGRID) * PT;

    for (int e = tid; e < PT * DIM; e += 256) {
      int r = e >> 6, k = e & 63;
      int gp = (p0 + r < SAMPLE ? p0 + r : 0) * SSTRIDE;
      int gq = (q0 + r < SAMPLE ? q0 + r : 0) * SSTRIDE;
      sm.p.EpT[k][r] = emb[(size_t)gp * DIM + k];
      sm.p.EqT[k][r] = emb[(size_t)gq * DIM + k];
    }
    if (tid < PT) {
      int g = (p0 + tid < SAMPLE ? p0 + tid : 0) * SSTRIDE;
      sm.p.Cp[tid][0] = coord[3 * g]; sm.p.Cp[tid][1] = coord[3 * g + 1];
      sm.p.Cp[tid][2] = coord[3 * g + 2];
    } else if (tid < 2 * PT) {
      int r = tid - PT;
      int g = (q0 + r < SAMPLE ? q0 + r : 0) * SSTRIDE;
      sm.p.Cq[r][0] = coord[3 * g]; sm.p.Cq[r][1] = coord[3 * g + 1];
      sm.p.Cq[r][2] = coord[3 * g + 2];
    }
    __syncthreads();

    float s[2][2] = {};
    #pragma unroll 8
    for (int k = 0; k < DIM; ++k) {
      float2 ep = *(const float2*)&sm.p.EpT[k][2 * ty];
      float2 eq = *(const float2*)&sm.p.EqT[k][2 * tx];
      float d;
      d = ep.x - eq.x; s[0][0] += d * d;
      d = ep.x - eq.y; s[0][1] += d * d;
      d = ep.y - eq.x; s[1][0] += d * d;
      d = ep.y - eq.y; s[1][1] += d * d;
    }

    double se = 0, sc = 0, se2 = 0, sc2 = 0, sec = 0;
    #pragma unroll
    for (int a = 0; a < 2; ++a)
      #pragma unroll
      for (int b = 0; b < 2; ++b) {
        int p = p0 + 2 * ty + a, q = q0 + 2 * tx + b;
        if (p < SAMPLE && q < SAMPLE) {
          float ed = sqrtf(fmaxf(s[a][b], 0.f));
          float dx = sm.p.Cp[2 * ty + a][0] - sm.p.Cq[2 * tx + b][0];
          float dy = sm.p.Cp[2 * ty + a][1] - sm.p.Cq[2 * tx + b][1];
          float dz = sm.p.Cp[2 * ty + a][2] - sm.p.Cq[2 * tx + b][2];
          float cd = sqrtf(fmaxf(dx * dx + dy * dy + dz * dz, 0.f));
          se += (double)ed; sc += (double)cd;
          se2 += (double)ed * ed; sc2 += (double)cd * cd;
          sec += (double)ed * cd;
        }
      }

    double vals[5] = { se, sc, se2, sc2, sec };
    #pragma unroll
    for (int v = 0; v < 5; ++v) {
      #pragma unroll
      for (int off = 32; off > 0; off >>= 1) vals[v] += __shfl_xor(vals[v], off, 64);
    }
    if (lane == 0) {
      #pragma unroll
      for (int v = 0; v < 5; ++v) sm.p.wred[wv][v] = vals[v];
    }
    __syncthreads();
    if (tid < 5) {
      double smv = sm.p.wred[0][tid] + sm.p.wred[1][tid] + sm.p.wred[2][tid] +
                   sm.p.wred[3][tid];
      atomicAdd(&acc[tid], smv);
    }
  }

  // ================= last-block finalize (device-scope counter) =============
  __syncthreads();           // all waves' global atomics issued & drained
  if (tid == 0) {
    __threadfence();
    unsigned old = atomicAdd(cnt, 1u);
    if (old == TOTAL_BLOCKS - 1) {
      double a[37];
      #pragma unroll 1
      for (int s = 0; s < 37; ++s) a[s] = atomicAdd(&acc[s], 0.0);  // coherent
      double M = (double)SAMPLE * (double)SAMPLE;
      double med = a[0] / M, mcd = a[1] / M;
      double ve = a[2] / M - med * med;
      double vc = a[3] / M - mcd * mcd;
      double es = sqrt(ve + 1e-8);
      double cs = sqrt(vc + 1e-8);
      double cov = a[4] / M - med * mcd;
      double pearson = cov / (es * cs + 1e-8);
      double lsum = 0.0;
      for (int s = 5; s < 37; ++s) lsum += a[s];
      double local = lsum / ((double)NPTS * (double)KNN);
      out[0] = (float)((1.0 - pearson) + 0.5 * local);
    }
  }
}

extern "C" void kernel_launch(void* const* d_in, const int* in_sizes, int n_in,
                              void* d_out, int out_size, void* d_ws, size_t ws_size,
                              hipStream_t stream) {
  const float* emb = (const float*)d_in[0];    // (12288, 64) f32
  const float* coord = (const float*)d_in[1];  // (12288, 3) f32
  double* acc = (double*)d_ws;

  hipMemsetAsync(d_ws, 0, 512, stream);        // acc[0..36] + done-counter

  fused_kernel<<<TOTAL_BLOCKS, NT, 0, stream>>>(emb, coord, acc, (float*)d_out);
}